// Round 9
// baseline (570.829 us; speedup 1.0000x reference)
//
#include <hip/hip_runtime.h>
#include <hip/hip_bf16.h>

typedef unsigned short u16;
typedef float v4f __attribute__((ext_vector_type(4)));
typedef __bf16 v8bf __attribute__((ext_vector_type(8)));
typedef unsigned short v4u __attribute__((ext_vector_type(4)));
typedef unsigned short v8u __attribute__((ext_vector_type(8)));

#define EMB 1024
#define TOK 4096
#define LSEQ 2048
#define NBATCH 2
#define SCALING 0.015625f
#define LN_EPS 1e-5f

__device__ __forceinline__ float bf2f(u16 u) {
  unsigned int i = ((unsigned int)u) << 16;
  return __builtin_bit_cast(float, i);
}
__device__ __forceinline__ u16 f2bf(float f) {
  __hip_bfloat16 h = __float2bfloat16(f);  // RNE
  return __builtin_bit_cast(u16, h);
}
__device__ __forceinline__ v8bf load8(const u16* p) {
  return *reinterpret_cast<const v8bf*>(p);
}
__device__ __forceinline__ v4f mfma16(v8bf a, v8bf b, v4f c) {
  return __builtin_amdgcn_mfma_f32_16x16x32_bf16(a, b, c, 0, 0, 0);
}
// async global->LDS, 16B/lane; LDS dest = wave-uniform base + lane*16
__device__ __forceinline__ void gload16(const u16* g, u16* l) {
  __builtin_amdgcn_global_load_lds(
      (const __attribute__((address_space(1))) void*)g,
      (__attribute__((address_space(3))) void*)l, 16, 0, 0);
}

// ---------------- fp32 -> bf16 weight conversion -------------------------
__global__ __launch_bounds__(256) void cvt_kernel(
    const float* __restrict__ in, u16* __restrict__ out) {
  size_t i = ((size_t)blockIdx.x * 256 + threadIdx.x) * 8;
  v4f a = *reinterpret_cast<const v4f*>(in + i);
  v4f b = *reinterpret_cast<const v4f*>(in + i + 4);
  v8u r;
#pragma unroll
  for (int j = 0; j < 4; j++) { r[j] = f2bf(a[j]); r[4 + j] = f2bf(b[j]); }
  *reinterpret_cast<v8u*>(out + i) = r;
}

// ---------------- LayerNorm: MODE 0 bf16-in, MODE 1 fp32-in -> bf16 out --
template <int MODE>
__global__ __launch_bounds__(256) void ln_kernel(
    const void* __restrict__ xin, const float* __restrict__ w,
    const float* __restrict__ b, u16* __restrict__ y) {
  int t = blockIdx.x, tid = threadIdx.x;
  float v[4];
  if (MODE == 0) {
    v4u raw = *reinterpret_cast<const v4u*>((const u16*)xin + (size_t)t * EMB + tid * 4);
#pragma unroll
    for (int j = 0; j < 4; j++) v[j] = bf2f(raw[j]);
  } else {
    v4f raw = *reinterpret_cast<const v4f*>((const float*)xin + (size_t)t * EMB + tid * 4);
#pragma unroll
    for (int j = 0; j < 4; j++) v[j] = raw[j];
  }
  float s = v[0] + v[1] + v[2] + v[3];
  float ss = v[0] * v[0] + v[1] * v[1] + v[2] * v[2] + v[3] * v[3];
#pragma unroll
  for (int off = 32; off >= 1; off >>= 1) {
    s += __shfl_xor(s, off);
    ss += __shfl_xor(ss, off);
  }
  __shared__ float sm[4], sq[4];
  if ((tid & 63) == 0) { sm[tid >> 6] = s; sq[tid >> 6] = ss; }
  __syncthreads();
  s = sm[0] + sm[1] + sm[2] + sm[3];
  ss = sq[0] + sq[1] + sq[2] + sq[3];
  float mu = s * (1.0f / EMB);
  float var = ss * (1.0f / EMB) - mu * mu;
  float rstd = rsqrtf(var + LN_EPS);
  v4f wv = *reinterpret_cast<const v4f*>(w + tid * 4);
  v4f bv = *reinterpret_cast<const v4f*>(b + tid * 4);
  v4u out;
#pragma unroll
  for (int j = 0; j < 4; j++) out[j] = f2bf((v[j] - mu) * rstd * wv[j] + bv[j]);
  *reinterpret_cast<v4u*>(y + (size_t)t * EMB + tid * 4) = out;
}

// ---------------- GEMM engine: C[M,N] = A_bf @ W_bf^T + bias -------------
// Grid transposed: row-tile on blockIdx.x so dispatch id%8 spreads rows
// across XCDs (R8: cut fc FETCH 139->42 MB).
// Tiles: <128,128> 2x2 waves 64x64 ; <64,128> 1x4 waves 64x32 ;
//        <128,256> 2x2 waves 64x128 (acc 4x8; 32 MFMA/barrier/wave —
//        doubles matrix work per sync for short-K shapes).
// Double-buffered LDS, one barrier per K-step. LDS group stride = n*2048.
// mode 1: out_bf = bf16(res_f32 + v)   mode 2: out_bf = gelu(v)
// mode 3: out_f  = bf2f(res_bf) + v    mode 4: qkv head-major scatter
template <int BM, int BN>
__global__ __launch_bounds__(256) void gemm_db_kernel(
    const u16* __restrict__ A, const u16* __restrict__ W,
    const float* __restrict__ bias, int K, int Nout, int mode,
    u16* __restrict__ out_bf, float* __restrict__ out_f,
    const float* __restrict__ res_f32, const u16* __restrict__ res_bf) {
  constexpr int NJ = BM * BN / 4096;   // col fragments per wave
  constexpr int CWV = 4 / (BM / 64);   // col-waves
  __shared__ alignas(16) u16 lA[2][BM * 32];  // [buf][seg][row][8]
  __shared__ alignas(16) u16 lB[2][BN * 32];  // [buf][seg][col][8]

  int tid = threadIdx.x;
  int lane = tid & 63, wid = tid >> 6;
  int quad = lane >> 4, l16 = lane & 15;
  int row0 = blockIdx.x * BM;
  int col0 = blockIdx.y * BN;
  int rw = (wid / CWV) * 64;
  int cw = (wid % CWV) * (BN / CWV);

  v4f zero = {0.f, 0.f, 0.f, 0.f};
  v4f acc[4][NJ];
#pragma unroll
  for (int i = 0; i < 4; i++)
#pragma unroll
    for (int j = 0; j < NJ; j++) acc[i][j] = zero;

  int wbase8 = (tid & 192) * 8;  // wave-uniform LDS slot base (u16 units)

  auto stage = [&](int buf, int k0) {
    const u16* Ab = A + (size_t)row0 * K + k0;
    const u16* Wb = W + (size_t)col0 * K + k0;
    // A: BM*4 slots of 16B, layout [seg][row][8]; group stride 2048 u16
#pragma unroll
    for (int n = 0; n < BM / 64; n++) {
      int slot = n * 256 + tid;
      int seg = slot / BM, r = slot & (BM - 1);
      gload16(Ab + (size_t)r * K + seg * 8, &lA[buf][n * 2048 + wbase8]);
    }
    // B: BN*4 slots, layout [seg][col][8]
#pragma unroll
    for (int n = 0; n < BN / 64; n++) {
      int slot = n * 256 + tid;
      int seg = slot / BN, r = slot & (BN - 1);
      gload16(Wb + (size_t)r * K + seg * 8, &lB[buf][n * 2048 + wbase8]);
    }
  };

  stage(0, 0);
  int buf = 0;
  for (int k0 = 0; k0 < K; k0 += 32) {
    __syncthreads();  // prefetch into buf landed; buf^1 free to overwrite
    if (k0 + 32 < K) stage(buf ^ 1, k0 + 32);

    v8bf af[4], bfr[NJ];
#pragma unroll
    for (int i = 0; i < 4; i++)
      af[i] = load8(&lA[buf][(quad * BM + rw + i * 16 + l16) * 8]);
#pragma unroll
    for (int j = 0; j < NJ; j++)
      bfr[j] = load8(&lB[buf][(quad * BN + cw + j * 16 + l16) * 8]);
#pragma unroll
    for (int i = 0; i < 4; i++)
#pragma unroll
      for (int j = 0; j < NJ; j++)
        acc[i][j] = mfma16(af[i], bfr[j], acc[i][j]);
    buf ^= 1;
  }

#pragma unroll
  for (int i = 0; i < 4; i++) {
    int rbase = row0 + rw + i * 16 + quad * 4;
#pragma unroll
    for (int j = 0; j < NJ; j++) {
      int c = col0 + cw + j * 16 + l16;
      float bv = bias[c];
#pragma unroll
      for (int r = 0; r < 4; r++) {
        int tok = rbase + r;
        float v = acc[i][j][r] + bv;
        if (mode == 4) {
          int region = c >> 10;  // 0=q,1=k,2=v
          int cc = c & 1023;
          int hh = cc >> 6, dd = cc & 63;
          int l = tok >> 1, nn = tok & 1;
          size_t hb = (size_t)(nn * 16 + hh);
          if (region == 0) {
            out_bf[(hb * LSEQ + l) * 64 + dd] = f2bf(v * SCALING);
          } else if (region == 1) {
            out_bf[4194304 + (hb * LSEQ + l) * 64 + dd] = f2bf(v);
          } else {
            out_bf[8388608 + (hb * 64 + dd) * LSEQ + l] = f2bf(v);
          }
        } else {
          size_t idx = (size_t)tok * Nout + c;
          if (mode == 1) {
            out_bf[idx] = f2bf(res_f32[idx] + v);
          } else if (mode == 2) {
            float g = 0.5f * v * (1.0f + erff(v * 0.70710678f));
            out_bf[idx] = f2bf(g);
          } else {
            out_f[idx] = bf2f(res_bf[idx]) + v;
          }
        }
      }
    }
  }
}

// ---------------- Flash attention (no-max softmax, swizzled LDS) ---------
// Inputs head-major: q,k (n,h,l,d) [q pre-scaled], vt (n,h,d,l).
__global__ __launch_bounds__(256) void flash_kernel(
    const u16* __restrict__ qb, const u16* __restrict__ kb,
    const u16* __restrict__ vtb, u16* __restrict__ o) {
  int tid = threadIdx.x;
  int lane = tid & 63, wid = tid >> 6;
  int quad = lane >> 4, l16 = lane & 15;
  int qt = blockIdx.x;
  int nh = blockIdx.y;
  int n = nh >> 4, h = nh & 15;

  __shared__ alignas(16) u16 lK[4096];
  __shared__ alignas(16) u16 lV[4096];
  __shared__ alignas(16) u16 pl[128][72];

  const u16* khead = kb + (size_t)nh * (LSEQ * 64);
  const u16* vhead = vtb + (size_t)nh * (64 * LSEQ);

  v4f zero = {0.f, 0.f, 0.f, 0.f};
  v4f acc_o[2][4];
  float lsum[2][4];
#pragma unroll
  for (int i = 0; i < 2; i++) {
#pragma unroll
    for (int r = 0; r < 4; r++) lsum[i][r] = 0.f;
#pragma unroll
    for (int jd = 0; jd < 4; jd++) acc_o[i][jd] = zero;
  }

  v8bf qf[2][2];
#pragma unroll
  for (int i = 0; i < 2; i++) {
    int lq = qt * 128 + wid * 32 + i * 16 + l16;
#pragma unroll
    for (int kk = 0; kk < 2; kk++)
      qf[i][kk] = load8(qb + ((size_t)nh * LSEQ + lq) * 64 + kk * 32 + quad * 8);
  }

  int swl = l16 & 7;
  int srow = tid >> 3;
  int sseg0 = tid & 7;
  int lbase = (tid & 192) * 8;

  for (int s0 = 0; s0 < LSEQ; s0 += 64) {
#pragma unroll
    for (int p = 0; p < 2; p++) {
      int row = p * 32 + srow;
      int seg = sseg0 ^ (row & 7);
      gload16(khead + (size_t)(s0 + row) * 64 + seg * 8, &lK[p * 2048 + lbase]);
      gload16(vhead + (size_t)row * LSEQ + s0 + seg * 8, &lV[p * 2048 + lbase]);
    }
    __syncthreads();

    v4f sacc[2][4];
#pragma unroll
    for (int i = 0; i < 2; i++)
#pragma unroll
      for (int j = 0; j < 4; j++) sacc[i][j] = zero;
#pragma unroll
    for (int kk = 0; kk < 2; kk++) {
      v8bf kf[4];
#pragma unroll
      for (int j = 0; j < 4; j++) {
        int rl = j * 16 + l16;
        kf[j] = load8(&lK[((rl << 3) + (((kk << 2) + quad) ^ swl)) << 3]);
      }
#pragma unroll
      for (int i = 0; i < 2; i++)
#pragma unroll
        for (int j = 0; j < 4; j++)
          sacc[i][j] = mfma16(qf[i][kk], kf[j], sacc[i][j]);
    }

#pragma unroll
    for (int i = 0; i < 2; i++) {
#pragma unroll
      for (int r = 0; r < 4; r++) {
        float ps = 0.f;
#pragma unroll
        for (int j = 0; j < 4; j++) {
          float p = __expf(fminf(sacc[i][j][r], 60.f));
          ps += p;
          pl[wid * 32 + i * 16 + quad * 4 + r][j * 16 + l16] = f2bf(p);
        }
        lsum[i][r] += ps;
      }
    }

#pragma unroll
    for (int kk = 0; kk < 2; kk++) {
      v8bf pf[2], vf[4];
#pragma unroll
      for (int i = 0; i < 2; i++)
        pf[i] = load8(&pl[wid * 32 + i * 16 + l16][kk * 32 + quad * 8]);
#pragma unroll
      for (int jd = 0; jd < 4; jd++) {
        int dl = jd * 16 + l16;
        vf[jd] = load8(&lV[((dl << 3) + (((kk << 2) + quad) ^ swl)) << 3]);
      }
#pragma unroll
      for (int i = 0; i < 2; i++)
#pragma unroll
        for (int jd = 0; jd < 4; jd++)
          acc_o[i][jd] = mfma16(pf[i], vf[jd], acc_o[i][jd]);
    }
    __syncthreads();
  }

#pragma unroll
  for (int i = 0; i < 2; i++) {
#pragma unroll
    for (int r = 0; r < 4; r++) {
      float s = lsum[i][r];
#pragma unroll
      for (int off = 1; off < 16; off <<= 1) s += __shfl_xor(s, off);
      float inv = 1.0f / s;
      int lq = qt * 128 + wid * 32 + i * 16 + quad * 4 + r;
      size_t t = (size_t)lq * NBATCH + n;
#pragma unroll
      for (int jd = 0; jd < 4; jd++)
        o[t * EMB + h * 64 + jd * 16 + l16] = f2bf(acc_o[i][jd][r] * inv);
    }
  }
}

// ---------------- launcher ----------------
extern "C" void kernel_launch(void* const* d_in, const int* in_sizes, int n_in,
                              void* d_out, int out_size, void* d_ws,
                              size_t ws_size, hipStream_t stream) {
  const float* x = (const float*)d_in[0];
  const float* ln1_w = (const float*)d_in[1];
  const float* ln1_b = (const float*)d_in[2];
  const float* in_proj_w = (const float*)d_in[3];
  const float* in_proj_b = (const float*)d_in[4];
  const float* out_w = (const float*)d_in[5];
  const float* out_b = (const float*)d_in[6];
  const float* ln2_w = (const float*)d_in[7];
  const float* ln2_b = (const float*)d_in[8];
  const float* fc_w = (const float*)d_in[9];
  const float* fc_b = (const float*)d_in[10];
  const float* proj_w = (const float*)d_in[11];
  const float* proj_b = (const float*)d_in[12];
  float* out = (float*)d_out;

  char* ws = (char*)d_ws;
  // wbuf [0,8) ; y/o/h [8,40) ; qkv head-major [16,40) ; x2 bf16 [40,48) ;
  // z [48,56).  56 MB peak (known-good budget).
  u16* wbuf = (u16*)(ws + 0);
  u16* y = (u16*)(ws + 8388608);
  u16* qkvh = (u16*)(ws + 16777216);
  u16* o = (u16*)(ws + 8388608);
  u16* hbuf = (u16*)(ws + 8388608);
  u16* x2 = (u16*)(ws + 41943040);
  u16* z = (u16*)(ws + 50331648);

  u16* qb = qkvh;
  u16* kb = qkvh + 4194304;
  u16* vtb = qkvh + 8388608;

  // 1. ln1(x) -> y
  ln_kernel<1><<<TOK, 256, 0, stream>>>((const void*)x, ln1_w, ln1_b, y);
  // 2. qkv = y @ in_proj^T + b, scattered head-major (q scaled). 3 blk/CU.
  cvt_kernel<<<1536, 256, 0, stream>>>(in_proj_w, wbuf);
  gemm_db_kernel<128, 128><<<dim3(32, 24), 256, 0, stream>>>(
      y, wbuf, in_proj_b, EMB, 3 * EMB, 4, qkvh, nullptr, nullptr, nullptr);
  // 3. attention -> o
  flash_kernel<<<dim3(16, 32), 256, 0, stream>>>(qb, kb, vtb, o);
  // 4. x2 = bf16(x + o @ out_w^T + out_b). 512 blocks, 2/CU.
  cvt_kernel<<<512, 256, 0, stream>>>(out_w, wbuf);
  gemm_db_kernel<64, 128><<<dim3(64, 8), 256, 0, stream>>>(
      o, wbuf, out_b, EMB, EMB, 1, x2, nullptr, x, nullptr);
  // 5. ln2(x2) -> z
  ln_kernel<0><<<TOK, 256, 0, stream>>>((const void*)x2, ln2_w, ln2_b, z);
  // 6. h = gelu(z @ fc_w^T + fc_b). 128x256 tile: 512 blocks, 2/CU,
  //    32 MFMA/barrier/wave (2x matrix work per sync vs 128x128).
  cvt_kernel<<<2048, 256, 0, stream>>>(fc_w, wbuf);
  gemm_db_kernel<128, 256><<<dim3(32, 16), 256, 0, stream>>>(
      z, wbuf, fc_b, EMB, 4 * EMB, 2, hbuf, nullptr, nullptr, nullptr);
  // 7. out = x2 + h @ proj_w^T + proj_b (fp32). Single-K (split-K reverted:
  //    R8 showed reduce+partial traffic ate the gain).
  cvt_kernel<<<2048, 256, 0, stream>>>(proj_w, wbuf);
  gemm_db_kernel<64, 128><<<dim3(64, 8), 256, 0, stream>>>(
      hbuf, wbuf, proj_b, 4 * EMB, EMB, 3, nullptr, out, x2 ? nullptr : nullptr, x2);
}

// Round 10
// 511.999 us; speedup vs baseline: 1.1149x; 1.1149x over previous
//
#include <hip/hip_runtime.h>
#include <hip/hip_bf16.h>

typedef unsigned short u16;
typedef float v4f __attribute__((ext_vector_type(4)));
typedef __bf16 v8bf __attribute__((ext_vector_type(8)));
typedef unsigned short v4u __attribute__((ext_vector_type(4)));
typedef unsigned short v8u __attribute__((ext_vector_type(8)));

#define EMB 1024
#define TOK 4096
#define LSEQ 2048
#define NBATCH 2
#define SCALING 0.015625f
#define LN_EPS 1e-5f

__device__ __forceinline__ float bf2f(u16 u) {
  unsigned int i = ((unsigned int)u) << 16;
  return __builtin_bit_cast(float, i);
}
__device__ __forceinline__ u16 f2bf(float f) {
  __hip_bfloat16 h = __float2bfloat16(f);  // RNE
  return __builtin_bit_cast(u16, h);
}
__device__ __forceinline__ v8bf load8(const u16* p) {
  return *reinterpret_cast<const v8bf*>(p);
}
__device__ __forceinline__ v4f mfma16(v8bf a, v8bf b, v4f c) {
  return __builtin_amdgcn_mfma_f32_16x16x32_bf16(a, b, c, 0, 0, 0);
}
// async global->LDS, 16B/lane; LDS dest = wave-uniform base + lane*16
__device__ __forceinline__ void gload16(const u16* g, u16* l) {
  __builtin_amdgcn_global_load_lds(
      (const __attribute__((address_space(1))) void*)g,
      (__attribute__((address_space(3))) void*)l, 16, 0, 0);
}
// fast GELU (tanh form, ~9 VALU ops, no divergence): max |err| ~3e-4,
// below bf16 quantization of h — replaces 64x erff in the fc epilogue
// (R8 counters: VALUBusy 21% vs MfmaUtil 11% — epilogue was half the kernel)
__device__ __forceinline__ float gelu_fast(float v) {
  float u = v * (0.7978845608f + 0.0356774081f * v * v);
  return v / (1.0f + __expf(-2.0f * u));
}

// ---------------- fp32 -> bf16 weight conversion -------------------------
__global__ __launch_bounds__(256) void cvt_kernel(
    const float* __restrict__ in, u16* __restrict__ out) {
  size_t i = ((size_t)blockIdx.x * 256 + threadIdx.x) * 8;
  v4f a = *reinterpret_cast<const v4f*>(in + i);
  v4f b = *reinterpret_cast<const v4f*>(in + i + 4);
  v8u r;
#pragma unroll
  for (int j = 0; j < 4; j++) { r[j] = f2bf(a[j]); r[4 + j] = f2bf(b[j]); }
  *reinterpret_cast<v8u*>(out + i) = r;
}

// ---------------- LayerNorm: MODE 0 bf16-in, MODE 1 fp32-in -> bf16 out --
template <int MODE>
__global__ __launch_bounds__(256) void ln_kernel(
    const void* __restrict__ xin, const float* __restrict__ w,
    const float* __restrict__ b, u16* __restrict__ y) {
  int t = blockIdx.x, tid = threadIdx.x;
  float v[4];
  if (MODE == 0) {
    v4u raw = *reinterpret_cast<const v4u*>((const u16*)xin + (size_t)t * EMB + tid * 4);
#pragma unroll
    for (int j = 0; j < 4; j++) v[j] = bf2f(raw[j]);
  } else {
    v4f raw = *reinterpret_cast<const v4f*>((const float*)xin + (size_t)t * EMB + tid * 4);
#pragma unroll
    for (int j = 0; j < 4; j++) v[j] = raw[j];
  }
  float s = v[0] + v[1] + v[2] + v[3];
  float ss = v[0] * v[0] + v[1] * v[1] + v[2] * v[2] + v[3] * v[3];
#pragma unroll
  for (int off = 32; off >= 1; off >>= 1) {
    s += __shfl_xor(s, off);
    ss += __shfl_xor(ss, off);
  }
  __shared__ float sm[4], sq[4];
  if ((tid & 63) == 0) { sm[tid >> 6] = s; sq[tid >> 6] = ss; }
  __syncthreads();
  s = sm[0] + sm[1] + sm[2] + sm[3];
  ss = sq[0] + sq[1] + sq[2] + sq[3];
  float mu = s * (1.0f / EMB);
  float var = ss * (1.0f / EMB) - mu * mu;
  float rstd = rsqrtf(var + LN_EPS);
  v4f wv = *reinterpret_cast<const v4f*>(w + tid * 4);
  v4f bv = *reinterpret_cast<const v4f*>(b + tid * 4);
  v4u out;
#pragma unroll
  for (int j = 0; j < 4; j++) out[j] = f2bf((v[j] - mu) * rstd * wv[j] + bv[j]);
  *reinterpret_cast<v4u*>(y + (size_t)t * EMB + tid * 4) = out;
}

// ---------------- GEMM engine: C[M,N] = A_bf @ W_bf^T + bias -------------
// Grid transposed: row-tile on blockIdx.x so dispatch id%8 spreads rows
// across XCDs (R8: cut fc FETCH 139->42 MB).
// Tiles: <128,128> 2x2 waves 64x64 (VGPR 76, 4 blk/CU at 1024-block grids —
//        R9 showed 128x256's VGPR 172 drops occupancy to 1 blk/CU: regress).
//        <64,128> 1x4 waves 64x32 (VGPR 44) for N=1024 512-block grids.
// Double-buffered LDS, one barrier per K-step. LDS group stride = n*2048.
// mode 1: out_bf = bf16(res_f32 + v)   mode 2: out_bf = gelu_fast(v)
// mode 3: out_f  = bf2f(res_bf) + v    mode 4: qkv head-major scatter
template <int BM, int BN>
__global__ __launch_bounds__(256) void gemm_db_kernel(
    const u16* __restrict__ A, const u16* __restrict__ W,
    const float* __restrict__ bias, int K, int Nout, int mode,
    u16* __restrict__ out_bf, float* __restrict__ out_f,
    const float* __restrict__ res_f32, const u16* __restrict__ res_bf) {
  constexpr int NJ = BM * BN / 4096;   // col fragments per wave
  constexpr int CWV = 4 / (BM / 64);   // col-waves
  __shared__ alignas(16) u16 lA[2][BM * 32];  // [buf][seg][row][8]
  __shared__ alignas(16) u16 lB[2][BN * 32];  // [buf][seg][col][8]

  int tid = threadIdx.x;
  int lane = tid & 63, wid = tid >> 6;
  int quad = lane >> 4, l16 = lane & 15;
  int row0 = blockIdx.x * BM;
  int col0 = blockIdx.y * BN;
  int rw = (wid / CWV) * 64;
  int cw = (wid % CWV) * (BN / CWV);

  v4f zero = {0.f, 0.f, 0.f, 0.f};
  v4f acc[4][NJ];
#pragma unroll
  for (int i = 0; i < 4; i++)
#pragma unroll
    for (int j = 0; j < NJ; j++) acc[i][j] = zero;

  int wbase8 = (tid & 192) * 8;  // wave-uniform LDS slot base (u16 units)

  auto stage = [&](int buf, int k0) {
    const u16* Ab = A + (size_t)row0 * K + k0;
    const u16* Wb = W + (size_t)col0 * K + k0;
    // A: BM*4 slots of 16B, layout [seg][row][8]; group stride 2048 u16
#pragma unroll
    for (int n = 0; n < BM / 64; n++) {
      int slot = n * 256 + tid;
      int seg = slot / BM, r = slot & (BM - 1);
      gload16(Ab + (size_t)r * K + seg * 8, &lA[buf][n * 2048 + wbase8]);
    }
    // B: BN*4 slots, layout [seg][col][8]
#pragma unroll
    for (int n = 0; n < BN / 64; n++) {
      int slot = n * 256 + tid;
      int seg = slot / BN, r = slot & (BN - 1);
      gload16(Wb + (size_t)r * K + seg * 8, &lB[buf][n * 2048 + wbase8]);
    }
  };

  stage(0, 0);
  int buf = 0;
  for (int k0 = 0; k0 < K; k0 += 32) {
    __syncthreads();  // prefetch into buf landed; buf^1 free to overwrite
    if (k0 + 32 < K) stage(buf ^ 1, k0 + 32);

    v8bf af[4], bfr[NJ];
#pragma unroll
    for (int i = 0; i < 4; i++)
      af[i] = load8(&lA[buf][(quad * BM + rw + i * 16 + l16) * 8]);
#pragma unroll
    for (int j = 0; j < NJ; j++)
      bfr[j] = load8(&lB[buf][(quad * BN + cw + j * 16 + l16) * 8]);
#pragma unroll
    for (int i = 0; i < 4; i++)
#pragma unroll
      for (int j = 0; j < NJ; j++)
        acc[i][j] = mfma16(af[i], bfr[j], acc[i][j]);
    buf ^= 1;
  }

#pragma unroll
  for (int i = 0; i < 4; i++) {
    int rbase = row0 + rw + i * 16 + quad * 4;
#pragma unroll
    for (int j = 0; j < NJ; j++) {
      int c = col0 + cw + j * 16 + l16;
      float bv = bias[c];
#pragma unroll
      for (int r = 0; r < 4; r++) {
        int tok = rbase + r;
        float v = acc[i][j][r] + bv;
        if (mode == 4) {
          int region = c >> 10;  // 0=q,1=k,2=v
          int cc = c & 1023;
          int hh = cc >> 6, dd = cc & 63;
          int l = tok >> 1, nn = tok & 1;
          size_t hb = (size_t)(nn * 16 + hh);
          if (region == 0) {
            out_bf[(hb * LSEQ + l) * 64 + dd] = f2bf(v * SCALING);
          } else if (region == 1) {
            out_bf[4194304 + (hb * LSEQ + l) * 64 + dd] = f2bf(v);
          } else {
            out_bf[8388608 + (hb * 64 + dd) * LSEQ + l] = f2bf(v);
          }
        } else {
          size_t idx = (size_t)tok * Nout + c;
          if (mode == 1) {
            out_bf[idx] = f2bf(res_f32[idx] + v);
          } else if (mode == 2) {
            out_bf[idx] = f2bf(gelu_fast(v));
          } else {
            out_f[idx] = bf2f(res_bf[idx]) + v;
          }
        }
      }
    }
  }
}

// ---------------- Flash attention (no-max softmax, swizzled LDS) ---------
// Inputs head-major: q,k (n,h,l,d) [q pre-scaled], vt (n,h,d,l).
__global__ __launch_bounds__(256) void flash_kernel(
    const u16* __restrict__ qb, const u16* __restrict__ kb,
    const u16* __restrict__ vtb, u16* __restrict__ o) {
  int tid = threadIdx.x;
  int lane = tid & 63, wid = tid >> 6;
  int quad = lane >> 4, l16 = lane & 15;
  int qt = blockIdx.x;
  int nh = blockIdx.y;
  int n = nh >> 4, h = nh & 15;

  __shared__ alignas(16) u16 lK[4096];
  __shared__ alignas(16) u16 lV[4096];
  __shared__ alignas(16) u16 pl[128][72];

  const u16* khead = kb + (size_t)nh * (LSEQ * 64);
  const u16* vhead = vtb + (size_t)nh * (64 * LSEQ);

  v4f zero = {0.f, 0.f, 0.f, 0.f};
  v4f acc_o[2][4];
  float lsum[2][4];
#pragma unroll
  for (int i = 0; i < 2; i++) {
#pragma unroll
    for (int r = 0; r < 4; r++) lsum[i][r] = 0.f;
#pragma unroll
    for (int jd = 0; jd < 4; jd++) acc_o[i][jd] = zero;
  }

  v8bf qf[2][2];
#pragma unroll
  for (int i = 0; i < 2; i++) {
    int lq = qt * 128 + wid * 32 + i * 16 + l16;
#pragma unroll
    for (int kk = 0; kk < 2; kk++)
      qf[i][kk] = load8(qb + ((size_t)nh * LSEQ + lq) * 64 + kk * 32 + quad * 8);
  }

  int swl = l16 & 7;
  int srow = tid >> 3;
  int sseg0 = tid & 7;
  int lbase = (tid & 192) * 8;

  for (int s0 = 0; s0 < LSEQ; s0 += 64) {
#pragma unroll
    for (int p = 0; p < 2; p++) {
      int row = p * 32 + srow;
      int seg = sseg0 ^ (row & 7);
      gload16(khead + (size_t)(s0 + row) * 64 + seg * 8, &lK[p * 2048 + lbase]);
      gload16(vhead + (size_t)row * LSEQ + s0 + seg * 8, &lV[p * 2048 + lbase]);
    }
    __syncthreads();

    v4f sacc[2][4];
#pragma unroll
    for (int i = 0; i < 2; i++)
#pragma unroll
      for (int j = 0; j < 4; j++) sacc[i][j] = zero;
#pragma unroll
    for (int kk = 0; kk < 2; kk++) {
      v8bf kf[4];
#pragma unroll
      for (int j = 0; j < 4; j++) {
        int rl = j * 16 + l16;
        kf[j] = load8(&lK[((rl << 3) + (((kk << 2) + quad) ^ swl)) << 3]);
      }
#pragma unroll
      for (int i = 0; i < 2; i++)
#pragma unroll
        for (int j = 0; j < 4; j++)
          sacc[i][j] = mfma16(qf[i][kk], kf[j], sacc[i][j]);
    }

#pragma unroll
    for (int i = 0; i < 2; i++) {
#pragma unroll
      for (int r = 0; r < 4; r++) {
        float ps = 0.f;
#pragma unroll
        for (int j = 0; j < 4; j++) {
          float p = __expf(fminf(sacc[i][j][r], 60.f));
          ps += p;
          pl[wid * 32 + i * 16 + quad * 4 + r][j * 16 + l16] = f2bf(p);
        }
        lsum[i][r] += ps;
      }
    }

#pragma unroll
    for (int kk = 0; kk < 2; kk++) {
      v8bf pf[2], vf[4];
#pragma unroll
      for (int i = 0; i < 2; i++)
        pf[i] = load8(&pl[wid * 32 + i * 16 + l16][kk * 32 + quad * 8]);
#pragma unroll
      for (int jd = 0; jd < 4; jd++) {
        int dl = jd * 16 + l16;
        vf[jd] = load8(&lV[((dl << 3) + (((kk << 2) + quad) ^ swl)) << 3]);
      }
#pragma unroll
      for (int i = 0; i < 2; i++)
#pragma unroll
        for (int jd = 0; jd < 4; jd++)
          acc_o[i][jd] = mfma16(pf[i], vf[jd], acc_o[i][jd]);
    }
    __syncthreads();
  }

#pragma unroll
  for (int i = 0; i < 2; i++) {
#pragma unroll
    for (int r = 0; r < 4; r++) {
      float s = lsum[i][r];
#pragma unroll
      for (int off = 1; off < 16; off <<= 1) s += __shfl_xor(s, off);
      float inv = 1.0f / s;
      int lq = qt * 128 + wid * 32 + i * 16 + quad * 4 + r;
      size_t t = (size_t)lq * NBATCH + n;
#pragma unroll
      for (int jd = 0; jd < 4; jd++)
        o[t * EMB + h * 64 + jd * 16 + l16] = f2bf(acc_o[i][jd][r] * inv);
    }
  }
}

// ---------------- launcher ----------------
extern "C" void kernel_launch(void* const* d_in, const int* in_sizes, int n_in,
                              void* d_out, int out_size, void* d_ws,
                              size_t ws_size, hipStream_t stream) {
  const float* x = (const float*)d_in[0];
  const float* ln1_w = (const float*)d_in[1];
  const float* ln1_b = (const float*)d_in[2];
  const float* in_proj_w = (const float*)d_in[3];
  const float* in_proj_b = (const float*)d_in[4];
  const float* out_w = (const float*)d_in[5];
  const float* out_b = (const float*)d_in[6];
  const float* ln2_w = (const float*)d_in[7];
  const float* ln2_b = (const float*)d_in[8];
  const float* fc_w = (const float*)d_in[9];
  const float* fc_b = (const float*)d_in[10];
  const float* proj_w = (const float*)d_in[11];
  const float* proj_b = (const float*)d_in[12];
  float* out = (float*)d_out;

  char* ws = (char*)d_ws;
  // wbuf [0,8) ; y/o/h [8,40) ; qkv head-major [16,40) ; x2 bf16 [40,48) ;
  // z [48,56).  56 MB peak (known-good budget).
  u16* wbuf = (u16*)(ws + 0);
  u16* y = (u16*)(ws + 8388608);
  u16* qkvh = (u16*)(ws + 16777216);
  u16* o = (u16*)(ws + 8388608);
  u16* hbuf = (u16*)(ws + 8388608);
  u16* x2 = (u16*)(ws + 41943040);
  u16* z = (u16*)(ws + 50331648);

  u16* qb = qkvh;
  u16* kb = qkvh + 4194304;
  u16* vtb = qkvh + 8388608;

  // 1. ln1(x) -> y
  ln_kernel<1><<<TOK, 256, 0, stream>>>((const void*)x, ln1_w, ln1_b, y);
  // 2. qkv = y @ in_proj^T + b, scattered head-major (q scaled). 3 blk/CU.
  cvt_kernel<<<1536, 256, 0, stream>>>(in_proj_w, wbuf);
  gemm_db_kernel<128, 128><<<dim3(32, 24), 256, 0, stream>>>(
      y, wbuf, in_proj_b, EMB, 3 * EMB, 4, qkvh, nullptr, nullptr, nullptr);
  // 3. attention -> o
  flash_kernel<<<dim3(16, 32), 256, 0, stream>>>(qb, kb, vtb, o);
  // 4. x2 = bf16(x + o @ out_w^T + out_b). 512 blocks, 2/CU.
  cvt_kernel<<<512, 256, 0, stream>>>(out_w, wbuf);
  gemm_db_kernel<64, 128><<<dim3(64, 8), 256, 0, stream>>>(
      o, wbuf, out_b, EMB, EMB, 1, x2, nullptr, x, nullptr);
  // 5. ln2(x2) -> z
  ln_kernel<0><<<TOK, 256, 0, stream>>>((const void*)x2, ln2_w, ln2_b, z);
  // 6. h = gelu_fast(z @ fc_w^T + fc_b). 128x128, 1024 blocks = 4/CU
  //    (R8 config: VGPR 76 keeps occupancy; R9's 128x256 regressed).
  cvt_kernel<<<2048, 256, 0, stream>>>(fc_w, wbuf);
  gemm_db_kernel<128, 128><<<dim3(32, 32), 256, 0, stream>>>(
      z, wbuf, fc_b, EMB, 4 * EMB, 2, hbuf, nullptr, nullptr, nullptr);
  // 7. out = x2 + h @ proj_w^T + proj_b (fp32). Single-K.
  cvt_kernel<<<2048, 256, 0, stream>>>(proj_w, wbuf);
  gemm_db_kernel<64, 128><<<dim3(64, 8), 256, 0, stream>>>(
      hbuf, wbuf, proj_b, 4 * EMB, EMB, 3, nullptr, out, nullptr, x2);
}